// Round 8
// baseline (276.928 us; speedup 1.0000x reference)
//
#include <hip/hip_runtime.h>
#include <math.h>

#define CH 512
#define P 8
#define PLANE 4096   // 64*64
#define EPS 1e-5f

typedef float f4 __attribute__((ext_vector_type(4)));

__device__ __forceinline__ float leaky(float x) { return x >= 0.f ? x : 0.01f * x; }

__device__ __forceinline__ float wave_sum(float v) {
    #pragma unroll
    for (int off = 32; off; off >>= 1) v += __shfl_xor(v, off, 64);
    return v;
}

// ---------------- Kernel 1a: s_d means + pk dot + S ----------------
// grid = N, block = 64
__global__ __launch_bounds__(64) void sd_pk_kernel(
    const float* __restrict__ style,   // [N,512,4,4]
    const float* __restrict__ pk_w,    // [8,512]
    const float* __restrict__ pk_b,    // [8]
    float* __restrict__ sd_out,        // [N,512]
    float* __restrict__ S_out)         // [N]
{
    const int n = blockIdx.x;
    const int lane = threadIdx.x;
    const float4* sp = (const float4*)(style + (size_t)n * 8192);
    float sd[8];
    #pragma unroll
    for (int i = 0; i < 8; ++i) {
        int c = lane + 64 * i;
        float4 a = sp[c * 4 + 0], b = sp[c * 4 + 1];
        float4 d = sp[c * 4 + 2], e = sp[c * 4 + 3];
        float s = a.x + a.y + a.z + a.w + b.x + b.y + b.z + b.w
                + d.x + d.y + d.z + d.w + e.x + e.y + e.z + e.w;
        sd[i] = s * (1.f / 16.f);
        sd_out[n * 512 + c] = sd[i];
    }
    float Ssum = 0.f;
    #pragma unroll
    for (int o = 0; o < 8; ++o) {
        float acc = 0.f;
        #pragma unroll
        for (int i = 0; i < 8; ++i)
            acc += pk_w[o * 512 + lane + 64 * i] * sd[i];
        Ssum += wave_sum(acc) + pk_b[o];
    }
    if (lane == 0) S_out[n] = Ssum;
}

// ---------------- Kernel 1b: depthwise-kernel predictor conv ----------------
// one wave per (n, j, tap); grid = 16*72/4 = 288, block = 256
__global__ __launch_bounds__(256) void dconv_kernel(
    const float* __restrict__ style,   // [N,512,4,4]
    const float* __restrict__ dw_w,    // [8,512,2,2]
    const float* __restrict__ dw_b,    // [8]
    float* __restrict__ d_pred)        // [N,72]
{
    const int W = blockIdx.x * 4 + (threadIdx.x >> 6);
    const int lane = threadIdx.x & 63;
    const int n = W / 72, r = W % 72;
    const int j = r / 9, pos = r % 9, y = pos / 3, x = pos % 3;
    const float* sb = style + (size_t)n * 8192;
    const float4* wp = (const float4*)dw_w;
    float acc = 0.f;
    #pragma unroll
    for (int i = 0; i < 8; ++i) {
        int c = lane + 64 * i;
        float4 w = wp[j * 512 + c];
        const float* s = sb + c * 16 + y * 4 + x;
        acc += s[0] * w.x + s[1] * w.y + s[4] * w.z + s[5] * w.w;
    }
    acc = wave_sum(acc);
    if (lane == 0) d_pred[n * 72 + r] = leaky(acc + dw_b[j]);
}

// ---------------- Kernel 1c: bias GEMV ----------------
// one wave per output channel c, all 16 n; grid = 512/4 = 128, block = 256
__global__ __launch_bounds__(256) void bias_kernel(
    const float* __restrict__ sd,      // [N,512]
    const float* __restrict__ pb_w,    // [512,512]
    const float* __restrict__ pb_b,    // [512]
    float* __restrict__ bias_out)      // [N,512]
{
    const int c = blockIdx.x * 4 + (threadIdx.x >> 6);
    const int lane = threadIdx.x & 63;
    float w[8];
    #pragma unroll
    for (int i = 0; i < 8; ++i) w[i] = pb_w[(size_t)c * 512 + lane + 64 * i];
    float acc[16];
    #pragma unroll
    for (int nn = 0; nn < 16; ++nn) acc[nn] = 0.f;
    #pragma unroll
    for (int i = 0; i < 8; ++i) {
        #pragma unroll
        for (int nn = 0; nn < 16; ++nn)
            acc[nn] += w[i] * sd[nn * 512 + lane + 64 * i];
    }
    #pragma unroll
    for (int nn = 0; nn < 16; ++nn) acc[nn] = wave_sum(acc[nn]);
    if (lane == 0) {
        float bb = pb_b[c];
        #pragma unroll
        for (int nn = 0; nn < 16; ++nn) bias_out[nn * 512 + c] = acc[nn] + bb;
    }
}

// ---------------- Kernel 2: per-(n,c) instance-norm stats ----------------
// grid = N*512, block = 256
__global__ __launch_bounds__(256) void stats_kernel(
    const float* __restrict__ content,   // [N,512,64,64]
    float* __restrict__ mean_out,        // [N*512]
    float* __restrict__ rstd_out)        // [N*512]
{
    const int nc = blockIdx.x;
    const int t = threadIdx.x;
    const float4* base = (const float4*)(content + (size_t)nc * PLANE);
    float s = 0.f, sq = 0.f;
    #pragma unroll
    for (int k = 0; k < 4; ++k) {
        float4 v = base[k * 256 + t];
        s  += v.x + v.y + v.z + v.w;
        sq += v.x * v.x + v.y * v.y + v.z * v.z + v.w * v.w;
    }
    #pragma unroll
    for (int off = 32; off > 0; off >>= 1) {
        s  += __shfl_down(s, off, 64);
        sq += __shfl_down(sq, off, 64);
    }
    __shared__ float ls[4], lq[4];
    const int wave = t >> 6, lane = t & 63;
    if (lane == 0) { ls[wave] = s; lq[wave] = sq; }
    __syncthreads();
    if (t == 0) {
        float S = ls[0] + ls[1] + ls[2] + ls[3];
        float Q = lq[0] + lq[1] + lq[2] + lq[3];
        float m = S * (1.f / 4096.f);
        float var = (Q - 4096.f * m * m) * (1.f / 4095.f);  // ddof=1
        mean_out[nc] = m;
        rstd_out[nc] = rsqrtf(var + EPS);
    }
}

// ---------------- Kernel 3: fused conv + pointwise-collapse + IN ----------------
// 2 output rows x 4 cols per thread: middle input rows shared between the two
// output rows -> per-pixel loads drop 0.75 -> 0.5, shfls likewise.
// Block = 256 (16 quads x 16 row-pairs = 32 rows). grid = N * 64 * 2 = 2048.
__global__ __launch_bounds__(256) void main_kernel(
    const float* __restrict__ content,   // [N,512,64,64]
    const float* __restrict__ d_pred,    // [N,72]
    const float* __restrict__ S_in,      // [N]
    const float* __restrict__ bias_in,   // [N,512]
    const float* __restrict__ mean_in,   // [N*512]
    const float* __restrict__ rstd_in,   // [N*512]
    float* __restrict__ out)             // [N,512,64,64]
{
    const int b    = blockIdx.x;
    const int tile = b & 1;
    const int g    = (b >> 1) & 63;
    const int n    = b >> 7;
    const int t  = threadIdx.x;
    const int tx = t & 15, ty = t >> 4;
    const int h0 = tile * 32 + ty * 2;   // this thread's two rows: h0, h0+1
    const int x0 = tx * 4;

    __shared__ float s_d[72];
    __shared__ float s_S;
    __shared__ float s_bias[8], s_mean[8], s_rstd[8];
    if (t < 72) s_d[t] = d_pred[n * 72 + t];
    if (t == 80) s_S = S_in[n];
    if (t >= 88 && t < 96) {
        int o = t - 88;
        int c = n * 512 + g * 8 + o;
        s_bias[o] = bias_in[c];
        s_mean[o] = mean_in[c];
        s_rstd[o] = rstd_in[c];
    }
    __syncthreads();

    const float* cbase = content + (size_t)(n * 512 + g * 8) * PLANE;
    float D00 = 0.f, D01 = 0.f, D02 = 0.f, D03 = 0.f;   // row h0
    float D10 = 0.f, D11 = 0.f, D12 = 0.f, D13 = 0.f;   // row h0+1
    f4 xc[8][2];   // center taps for both rows, all 8 channels

    #pragma unroll
    for (int j = 0; j < 8; ++j) {
        const float* cj = cbase + j * PLANE;
        f4 v[4];
        float xm[4], xp[4];
        #pragma unroll
        for (int k = 0; k < 4; ++k) {     // input rows h0-1 .. h0+2
            int y = h0 - 1 + k;
            int ry = y < 0 ? 1 : (y > 63 ? 62 : y);   // reflect pad
            v[k] = *(const f4*)(cj + ry * 64 + x0);
            // x-halo from neighbor threads (same row-of-16); edges reflect
            float lv = __shfl_up(v[k].w, 1, 64);
            float rv = __shfl_down(v[k].x, 1, 64);
            xm[k] = (tx == 0)  ? v[k].y : lv;   // x=-1 -> 1
            xp[k] = (tx == 15) ? v[k].z : rv;   // x=64 -> 62
        }
        xc[j][0] = v[1];
        xc[j][1] = v[2];
        #pragma unroll
        for (int r = 0; r < 3; ++r) {
            const float w0 = s_d[j * 9 + r * 3 + 0];
            const float w1 = s_d[j * 9 + r * 3 + 1];
            const float w2 = s_d[j * 9 + r * 3 + 2];
            // output row h0 consumes input rows r(0..2); h0+1 consumes r+1
            D00 += w0 * xm[r]     + w1 * v[r].x   + w2 * v[r].y;
            D01 += w0 * v[r].x    + w1 * v[r].y   + w2 * v[r].z;
            D02 += w0 * v[r].y    + w1 * v[r].z   + w2 * v[r].w;
            D03 += w0 * v[r].z    + w1 * v[r].w   + w2 * xp[r];
            D10 += w0 * xm[r+1]   + w1 * v[r+1].x + w2 * v[r+1].y;
            D11 += w0 * v[r+1].x  + w1 * v[r+1].y + w2 * v[r+1].z;
            D12 += w0 * v[r+1].y  + w1 * v[r+1].z + w2 * v[r+1].w;
            D13 += w0 * v[r+1].z  + w1 * v[r+1].w + w2 * xp[r+1];
        }
    }

    const float S = s_S;
    const float P00 = D00 * S, P01 = D01 * S, P02 = D02 * S, P03 = D03 * S;
    const float P10 = D10 * S, P11 = D11 * S, P12 = D12 * S, P13 = D13 * S;
    float* obase = out + (size_t)(n * 512 + g * 8) * PLANE + h0 * 64 + x0;
    #pragma unroll
    for (int o = 0; o < 8; ++o) {
        float bb = s_bias[o], m = s_mean[o], rs = s_rstd[o];
        f4 r0, r1;
        r0.x = (xc[o][0].x - m) * rs * leaky(P00 + bb);
        r0.y = (xc[o][0].y - m) * rs * leaky(P01 + bb);
        r0.z = (xc[o][0].z - m) * rs * leaky(P02 + bb);
        r0.w = (xc[o][0].w - m) * rs * leaky(P03 + bb);
        r1.x = (xc[o][1].x - m) * rs * leaky(P10 + bb);
        r1.y = (xc[o][1].y - m) * rs * leaky(P11 + bb);
        r1.z = (xc[o][1].z - m) * rs * leaky(P12 + bb);
        r1.w = (xc[o][1].w - m) * rs * leaky(P13 + bb);
        // NT stores: avoid write-allocate amplification (R6 evidence: 2.6x)
        __builtin_nontemporal_store(r0, (f4*)(obase + o * PLANE));
        __builtin_nontemporal_store(r1, (f4*)(obase + o * PLANE + 64));
    }
}

extern "C" void kernel_launch(void* const* d_in, const int* in_sizes, int n_in,
                              void* d_out, int out_size, void* d_ws, size_t ws_size,
                              hipStream_t stream) {
    const float* style   = (const float*)d_in[0];
    const float* content = (const float*)d_in[1];
    const float* dw_w    = (const float*)d_in[2];
    const float* dw_b    = (const float*)d_in[3];
    const float* pk_w    = (const float*)d_in[4];
    const float* pk_b    = (const float*)d_in[5];
    const float* pb_w    = (const float*)d_in[6];
    const float* pb_b    = (const float*)d_in[7];
    float* out = (float*)d_out;
    float* ws  = (float*)d_ws;

    const int N = 16;
    float* sd_ws   = ws;                  // N*512
    float* d_pred  = sd_ws + N * 512;     // N*72
    float* S_ws    = d_pred + N * 72;     // N
    float* bias_ws = S_ws + N;            // N*512
    float* mean_ws = bias_ws + N * 512;   // N*512
    float* rstd_ws = mean_ws + N * 512;   // N*512

    sd_pk_kernel<<<N, 64, 0, stream>>>(style, pk_w, pk_b, sd_ws, S_ws);
    dconv_kernel<<<N * 72 / 4, 256, 0, stream>>>(style, dw_w, dw_b, d_pred);
    bias_kernel<<<512 / 4, 256, 0, stream>>>(sd_ws, pb_w, pb_b, bias_ws);
    stats_kernel<<<N * 512, 256, 0, stream>>>(content, mean_ws, rstd_ws);
    main_kernel<<<N * 64 * 2, 256, 0, stream>>>(content, d_pred, S_ws, bias_ws,
                                                mean_ws, rstd_ws, out);
}